// Round 1
// baseline (2163.964 us; speedup 1.0000x reference)
//
#include <hip/hip_runtime.h>
#include <math.h>

// NonlocalWeightedAverage, fused flash-softmax formulation.
// corr[m,n] = sum_{dy,dx,c} f[c,ym+dy-1,xm+dx-1]*f[c,yn+dy-1,xn+dx-1] (zero-padded)
// out[b,:,m] = softmax_n(corr[m,:]*10) @ x_ab[n,:]
//
// Block = (b, ym): 64 m-pixels (one image row). 256 threads = 16x16,
// each thread owns a 4x4 corr sub-tile. Online softmax over 64 n-tiles
// (one image row of n each). LDS holds 3-row zero-padded feature slabs.

#define B_ 4
#define CH 64
#define H_ 64
#define W_ 64
#define WP 68          // padded width: idx 0..67 <-> x=-1..66, zeros outside [0,64)
#define SCALE 10.0f    // 1/ALPHA

__global__ __launch_bounds__(256) void nlwa_fused(
    const float* __restrict__ xlab,   // [B,3,H,W]
    const float* __restrict__ feat,   // [B,CH,H,W]
    float* __restrict__ out)          // [B,2,H,W]
{
    const int b   = blockIdx.y;
    const int ym  = blockIdx.x;
    const int tid = (int)threadIdx.x;
    const int tn  = tid & 15;   // n-tile position (4 n's)
    const int tm  = tid >> 4;   // m position (4 m's)

    __shared__ float smA[3][CH][WP];
    __shared__ float smB[3][CH][WP];

    const float* fb  = feat + (size_t)b * CH * H_ * W_;
    const float* aab = xlab + ((size_t)b * 3 + 1) * H_ * W_;
    const float* bab = xlab + ((size_t)b * 3 + 2) * H_ * W_;

    // Stage A slab: feature rows ym-1..ym+1, zero-padded. 3*64*68/256 = 51 per thread.
    for (int idx = tid; idx < 3 * CH * WP; idx += 256) {
        int dy = idx / (CH * WP);
        int r  = idx - dy * (CH * WP);
        int c  = r / WP;
        int xx = r - c * WP;
        int y = ym + dy - 1;
        int x = xx - 1;
        float v = 0.0f;
        if ((unsigned)y < H_ && (unsigned)x < W_) v = fb[(c * H_ + y) * W_ + x];
        smA[dy][c][xx] = v;
    }

    float runM[4], runS[4], runW0[4], runW1[4];
    #pragma unroll
    for (int i = 0; i < 4; ++i) { runM[i] = -INFINITY; runS[i] = 0.f; runW0[i] = 0.f; runW1[i] = 0.f; }

    __syncthreads();

    for (int yn = 0; yn < H_; ++yn) {
        // Stage B slab: feature rows yn-1..yn+1
        for (int idx = tid; idx < 3 * CH * WP; idx += 256) {
            int dy = idx / (CH * WP);
            int r  = idx - dy * (CH * WP);
            int c  = r / WP;
            int xx = r - c * WP;
            int y = yn + dy - 1;
            int x = xx - 1;
            float v = 0.0f;
            if ((unsigned)y < H_ && (unsigned)x < W_) v = fb[(c * H_ + y) * W_ + x];
            smB[dy][c][xx] = v;
        }
        __syncthreads();

        float acc[4][4];
        #pragma unroll
        for (int i = 0; i < 4; ++i)
            #pragma unroll
            for (int j = 0; j < 4; ++j) acc[i][j] = 0.0f;

        // K-loop: 6-wide windows cover all three dx shifts -> 12 LDS floats / 48 FMA.
        #pragma unroll 1
        for (int dy = 0; dy < 3; ++dy) {
            const float* pa = &smA[dy][0][tm << 2];
            const float* pb = &smB[dy][0][tn << 2];
            #pragma unroll 4
            for (int c = 0; c < CH; ++c) {
                float a[6], g[6];
                #pragma unroll
                for (int t = 0; t < 6; ++t) {
                    a[t] = pa[c * WP + t];
                    g[t] = pb[c * WP + t];
                }
                #pragma unroll
                for (int dx = 0; dx < 3; ++dx)
                    #pragma unroll
                    for (int i = 0; i < 4; ++i)
                        #pragma unroll
                        for (int j = 0; j < 4; ++j)
                            acc[i][j] += a[i + dx] * g[j + dx];
            }
        }

        // ab-channel values for this n-tile
        float av[4], bv[4];
        #pragma unroll
        for (int j = 0; j < 4; ++j) {
            int xn = (tn << 2) + j;
            av[j] = aab[yn * W_ + xn];
            bv[j] = bab[yn * W_ + xn];
        }

        // Online softmax update. Rows of the 64x64 tile live on 16 contiguous
        // lanes (same tm) -> 16-lane xor-shuffle reductions.
        #pragma unroll
        for (int i = 0; i < 4; ++i) {
            float v0 = acc[i][0] * SCALE;
            float v1 = acc[i][1] * SCALE;
            float v2 = acc[i][2] * SCALE;
            float v3 = acc[i][3] * SCALE;
            float tmax = fmaxf(fmaxf(v0, v1), fmaxf(v2, v3));
            #pragma unroll
            for (int off = 8; off >= 1; off >>= 1)
                tmax = fmaxf(tmax, __shfl_xor(tmax, off));
            float nm = fmaxf(runM[i], tmax);
            float p0 = __expf(v0 - nm);
            float p1 = __expf(v1 - nm);
            float p2 = __expf(v2 - nm);
            float p3 = __expf(v3 - nm);
            float ps  = p0 + p1 + p2 + p3;
            float pw0 = p0 * av[0] + p1 * av[1] + p2 * av[2] + p3 * av[3];
            float pw1 = p0 * bv[0] + p1 * bv[1] + p2 * bv[2] + p3 * bv[3];
            #pragma unroll
            for (int off = 8; off >= 1; off >>= 1) {
                ps  += __shfl_xor(ps,  off);
                pw0 += __shfl_xor(pw0, off);
                pw1 += __shfl_xor(pw1, off);
            }
            float sc = __expf(runM[i] - nm);  // exp(-inf)=0 on first tile
            runS[i]  = runS[i]  * sc + ps;
            runW0[i] = runW0[i] * sc + pw0;
            runW1[i] = runW1[i] * sc + pw1;
            runM[i]  = nm;
        }
        __syncthreads();   // smB consumed; safe to restage next iteration
    }

    if (tn == 0) {
        #pragma unroll
        for (int i = 0; i < 4; ++i) {
            int xm = (tm << 2) + i;
            float inv = 1.0f / runS[i];
            out[((b * 2 + 0) * H_ + ym) * W_ + xm] = runW0[i] * inv;
            out[((b * 2 + 1) * H_ + ym) * W_ + xm] = runW1[i] * inv;
        }
    }
}

extern "C" void kernel_launch(void* const* d_in, const int* in_sizes, int n_in,
                              void* d_out, int out_size, void* d_ws, size_t ws_size,
                              hipStream_t stream) {
    const float* xlab = (const float*)d_in[0];
    const float* feat = (const float*)d_in[1];
    float* out = (float*)d_out;
    dim3 grid(H_, B_);   // 64 ym-rows x 4 batches = 256 blocks
    nlwa_fused<<<grid, 256, 0, stream>>>(xlab, feat, out);
}

// Round 3
// 151.577 us; speedup vs baseline: 14.2763x; 14.2763x over previous
//
#include <hip/hip_runtime.h>
#include <math.h>

// NonlocalWeightedAverage via bf16 MFMA flash-attention.
// corr[m,n] = <lf_m, lf_n>, lf = 3x3 unfolded feature (K = 9*64 = 576).
// k ordering: k = s*64 + c, s = dy*3+dx (shift), c = channel. Any consistent
// ordering is valid (inner product), and corr is symmetric, so operand-layout
// transposes self-cancel.
//
// Kernel 1: feat [B,C,H,W] f32 -> tf [B,H,W,C] bf16 (d_ws), so a fragment's
//           8 contiguous channels are one 16B load.
// Kernel 2: block=(b,ym). 4 waves = 2(m-tile 32) x 2(n-half 32).
//           A-frags (36 x short8) hoisted to VGPRs. B from an LDS ring slab
//           [4 rows][66 xx][64 c] bf16, XOR-swizzled byte^=(xx&7)<<4.
//           Per-lane-local online softmax; butterfly + LDS merge at end.

#define B_ 4
#define CH 64
#define H_ 64
#define W_ 64
#define SCALE2 14.426950408889634f   // (1/ALPHA=10) * log2(e); exp2-based softmax
#define SLAB_ROW_BYTES (66 * 128)    // 66 xx-positions * 64ch * 2B = 8448

typedef __attribute__((ext_vector_type(8)))  short  short8;
typedef __attribute__((ext_vector_type(16))) float  f32x16;
typedef __attribute__((ext_vector_type(4)))  unsigned int uint4v;

__global__ __launch_bounds__(256) void feat_to_bf16(
    const float* __restrict__ feat, unsigned short* __restrict__ tf)
{
    const int b = blockIdx.y, y = blockIdx.x, t = (int)threadIdx.x;
    __shared__ float ld[CH][W_ + 1];
    #pragma unroll
    for (int i = 0; i < 16; ++i) {
        int idx = i * 256 + t;
        int c = idx >> 6, x = idx & 63;
        ld[c][x] = feat[(((size_t)b * CH + c) * H_ + y) * W_ + x];
    }
    __syncthreads();
    const int x = t >> 2, cq = t & 3;
    unsigned int p[8];
    #pragma unroll
    for (int k = 0; k < 8; ++k) {
        unsigned int w[2];
        #pragma unroll
        for (int e = 0; e < 2; ++e) {
            float f = ld[cq * 16 + 2 * k + e][x];
            unsigned int u = __float_as_uint(f);
            u += 0x7fff + ((u >> 16) & 1);      // RNE to bf16
            w[e] = u >> 16;
        }
        p[k] = w[0] | (w[1] << 16);
    }
    unsigned short* dst = &tf[(((size_t)b * H_ + y) * W_ + x) * CH + cq * 16];
    ((uint4v*)dst)[0] = (uint4v){p[0], p[1], p[2], p[3]};
    ((uint4v*)dst)[1] = (uint4v){p[4], p[5], p[6], p[7]};
}

__global__ __launch_bounds__(256, 1) void nlwa_mfma(
    const float* __restrict__ xlab,
    const unsigned short* __restrict__ tf,
    float* __restrict__ out)
{
    const int b = blockIdx.y, ym = blockIdx.x;
    const int tid = (int)threadIdx.x;
    const int w = tid >> 6;          // wave id: (mtile = w>>1, nhalf = w&1)
    const int l = tid & 63;
    const int l31 = l & 31, h = l >> 5;

    __shared__ char slab[4 * SLAB_ROW_BYTES];   // ring of 4 feature rows (bf16)
    __shared__ float4 mergebuf[2][64];

    const unsigned short* tfb = tf + (size_t)b * H_ * W_ * CH;
    const float* aab = xlab + ((size_t)b * 3 + 1) * H_ * W_;
    const float* bab = xlab + ((size_t)b * 3 + 2) * H_ * W_;

    // ---- zero the xx=0 / xx=65 pad columns of all 4 ring slots (once) ----
    if (tid < 64) {
        int slot = tid >> 4, which = (tid >> 3) & 1, chunk = tid & 7;
        int xx = which ? 65 : 0;
        int off = (xx * 128 + chunk * 16) ^ ((xx & 7) << 4);
        *(uint4v*)(slab + slot * SLAB_ROW_BYTES + off) = (uint4v){0, 0, 0, 0};
    }

    // ---- staging: one feature row (bf16) into ring slot y&3, swizzled ----
    auto stage_row = [&](int y) {
        int slot = y & 3;
        char* base = slab + slot * SLAB_ROW_BYTES;
        bool zero = (y < 0) || (y >= H_);
        #pragma unroll
        for (int i = 0; i < 2; ++i) {
            int cid = i * 256 + tid;            // 0..511 = 64 x * 8 c-groups
            int xx = 1 + (cid >> 3);
            int q8 = cid & 7;
            int off = (xx * 128 + q8 * 16) ^ ((xx & 7) << 4);
            uint4v v = (uint4v){0, 0, 0, 0};
            if (!zero)
                v = *(const uint4v*)&tfb[((size_t)y * W_ + (xx - 1)) * CH + q8 * 8];
            *(uint4v*)(base + off) = v;
        }
    };

    // ---- A-fragments: 36 kk-steps, loop-invariant per block ----
    // A lane layout (32x32x16): row = l&31, k = 8*(l>>5) + 2r + e (contiguous 8).
    short8 afrag[36];
    {
        const int xm = ((w >> 1) << 5) + l31;
        #pragma unroll
        for (int s = 0; s < 9; ++s) {
            int dy = s / 3, dx = s % 3;
            int y = ym + dy - 1, x = xm + dx - 1;
            bool valid = ((unsigned)y < H_) && ((unsigned)x < W_);
            #pragma unroll
            for (int q = 0; q < 4; ++q) {
                int cb = q * 16 + h * 8;
                short8 v = {0, 0, 0, 0, 0, 0, 0, 0};
                if (valid)
                    v = *(const short8*)&tfb[((size_t)(y * W_ + x)) * CH + cb];
                afrag[s * 4 + q] = v;
            }
        }
    }

    stage_row(-1); stage_row(0); stage_row(1);

    // ---- per-lane-local online softmax state: 16 rows x (this lane's n) ----
    float M[16], S[16], W0[16], W1[16];
    #pragma unroll
    for (int r = 0; r < 16; ++r) { M[r] = -INFINITY; S[r] = 0.f; W0[r] = 0.f; W1[r] = 0.f; }

    const int xn = ((w & 1) << 5) + l31;

    __syncthreads();

    for (int yn = 0; yn < H_; ++yn) {
        if (yn + 2 <= H_) stage_row(yn + 2);    // 2 iters ahead (y=64 -> zeros)

        const char* r0 = slab + ((yn - 1) & 3) * SLAB_ROW_BYTES;
        const char* r1 = slab + ((yn    ) & 3) * SLAB_ROW_BYTES;
        const char* r2 = slab + ((yn + 1) & 3) * SLAB_ROW_BYTES;

        f32x16 acc;
        #pragma unroll
        for (int r = 0; r < 16; ++r) acc[r] = 0.f;

        #pragma unroll
        for (int s = 0; s < 9; ++s) {
            const char* rb = (s < 3) ? r0 : ((s < 6) ? r1 : r2);
            int dx = s % 3;
            int xx = xn + dx;                   // 0..65
            int xb = xx * 128;
            int msk = (xx & 7) << 4;
            #pragma unroll
            for (int q = 0; q < 4; ++q) {
                int off = (q * 32 + h * 16) ^ msk;
                short8 bfrag = *(const short8*)(rb + xb + off);
                acc = __builtin_amdgcn_mfma_f32_32x32x16_bf16(
                          afrag[s * 4 + q], bfrag, acc, 0, 0, 0);
            }
        }

        float av = aab[yn * W_ + xn];
        float bv = bab[yn * W_ + xn];

        // D layout (32x32): col(n) = lane&31, row = (r&3)+8*(r>>2)+4*(lane>>5)
        #pragma unroll
        for (int r = 0; r < 16; ++r) {
            float v  = acc[r] * SCALE2;
            float nm = fmaxf(M[r], v);
            float sc = exp2f(M[r] - nm);        // exp2(-inf)=0 on first hit
            float p  = exp2f(v - nm);
            S[r]  = S[r]  * sc + p;
            W0[r] = W0[r] * sc + p * av;
            W1[r] = W1[r] * sc + p * bv;
            M[r]  = nm;
        }
        __syncthreads();
    }

    // ---- butterfly merge across the 32 n-columns within each half-wave ----
    #pragma unroll
    for (int off = 16; off >= 1; off >>= 1) {
        #pragma unroll
        for (int r = 0; r < 16; ++r) {
            float Mo  = __shfl_xor(M[r],  off);
            float So  = __shfl_xor(S[r],  off);
            float W0o = __shfl_xor(W0[r], off);
            float W1o = __shfl_xor(W1[r], off);
            float nm = fmaxf(M[r], Mo);
            float sA = exp2f(M[r] - nm), sB = exp2f(Mo - nm);
            S[r]  = S[r]  * sA + So  * sB;
            W0[r] = W0[r] * sA + W0o * sB;
            W1[r] = W1[r] * sA + W1o * sB;
            M[r]  = nm;
        }
    }

    if (l31 == 0) {
        #pragma unroll
        for (int r = 0; r < 16; ++r) {
            int mloc = (r & 3) + ((r >> 2) << 3) + (h << 2);
            int m = ((w >> 1) << 5) + mloc;
            mergebuf[w & 1][m] = make_float4(M[r], S[r], W0[r], W1[r]);
        }
    }
    __syncthreads();

    if (tid < 64) {
        float4 A  = mergebuf[0][tid];
        float4 Bv = mergebuf[1][tid];
        float nm = fmaxf(A.x, Bv.x);
        float sA = exp2f(A.x - nm), sB = exp2f(Bv.x - nm);
        float Ssum = A.y * sA + Bv.y * sB;
        float w0   = A.z * sA + Bv.z * sB;
        float w1   = A.w * sA + Bv.w * sB;
        out[(((size_t)b * 2 + 0) * H_ + ym) * W_ + tid] = w0 / Ssum;
        out[(((size_t)b * 2 + 1) * H_ + ym) * W_ + tid] = w1 / Ssum;
    }
}

extern "C" void kernel_launch(void* const* d_in, const int* in_sizes, int n_in,
                              void* d_out, int out_size, void* d_ws, size_t ws_size,
                              hipStream_t stream) {
    const float* xlab = (const float*)d_in[0];
    const float* feat = (const float*)d_in[1];
    float* out = (float*)d_out;
    unsigned short* tf = (unsigned short*)d_ws;   // 4*64*64*64*2 = 2 MB

    dim3 grid(H_, B_);
    feat_to_bf16<<<grid, 256, 0, stream>>>(feat, tf);
    nlwa_mfma<<<grid, 256, 0, stream>>>(xlab, tf, out);
}

// Round 4
// 118.842 us; speedup vs baseline: 18.2088x; 1.2754x over previous
//
#include <hip/hip_runtime.h>
#include <math.h>

// NonlocalWeightedAverage via bf16 MFMA flash-attention.
// corr[m,n] = <lf_m, lf_n>, lf = 3x3 unfolded feature (K = 9*64 = 576).
// R4: A-fragments served from a second LDS slab (kills the R3 VGPR spill of
// afrag[36]); yn-range split across 2 blocks (grid 512 = 2 blocks/CU) with a
// tiny final merge kernel; dual MFMA accumulators to break the dep chain.

#define B_ 4
#define CH 64
#define H_ 64
#define W_ 64
#define SCALE2 14.426950408889634f   // (1/ALPHA=10) * log2(e); exp2-based softmax
#define ROWB (66 * 128)              // one slab row: 66 xx * 64ch * 2B = 8448

typedef __attribute__((ext_vector_type(8)))  short  short8;
typedef __attribute__((ext_vector_type(16))) float  f32x16;
typedef __attribute__((ext_vector_type(4)))  unsigned int uint4v;

__global__ __launch_bounds__(256) void feat_to_bf16(
    const float* __restrict__ feat, unsigned short* __restrict__ tf)
{
    const int b = blockIdx.y, y = blockIdx.x, t = (int)threadIdx.x;
    __shared__ float ld[CH][W_ + 1];
    #pragma unroll
    for (int i = 0; i < 16; ++i) {
        int idx = i * 256 + t;
        int c = idx >> 6, x = idx & 63;
        ld[c][x] = feat[(((size_t)b * CH + c) * H_ + y) * W_ + x];
    }
    __syncthreads();
    const int x = t >> 2, cq = t & 3;
    unsigned int p[8];
    #pragma unroll
    for (int k = 0; k < 8; ++k) {
        unsigned int w[2];
        #pragma unroll
        for (int e = 0; e < 2; ++e) {
            float f = ld[cq * 16 + 2 * k + e][x];
            unsigned int u = __float_as_uint(f);
            u += 0x7fff + ((u >> 16) & 1);      // RNE to bf16
            w[e] = u >> 16;
        }
        p[k] = w[0] | (w[1] << 16);
    }
    unsigned short* dst = &tf[(((size_t)b * H_ + y) * W_ + x) * CH + cq * 16];
    ((uint4v*)dst)[0] = (uint4v){p[0], p[1], p[2], p[3]};
    ((uint4v*)dst)[1] = (uint4v){p[4], p[5], p[6], p[7]};
}

__global__ __launch_bounds__(256, 2) void nlwa_mfma(
    const float* __restrict__ xlab,
    const unsigned short* __restrict__ tf,
    float4* __restrict__ part)        // [B][H][2 z][64 m]
{
    const int b = blockIdx.y, ym = blockIdx.x, z = blockIdx.z;
    const int tid = (int)threadIdx.x;
    const int w = tid >> 6;          // wave: mtile = w>>1, nhalf = w&1
    const int l = tid & 63;
    const int l31 = l & 31, h = l >> 5;
    const int lo = z << 5;           // this block's yn range: [lo, lo+32)

    __shared__ __attribute__((aligned(16))) char slab[4 * ROWB];   // B ring
    __shared__ __attribute__((aligned(16))) char aslab[3 * ROWB];  // A rows ym-1..ym+1
    __shared__ float4 mergebuf[2][64];

    const unsigned short* tfb = tf + (size_t)b * H_ * W_ * CH;
    const float* aab = xlab + ((size_t)b * 3 + 1) * H_ * W_;
    const float* bab = xlab + ((size_t)b * 3 + 2) * H_ * W_;

    // ---- zero pad columns xx=0/65: B ring (4 slots) + A slab (3 slots) ----
    if (tid < 64) {
        int slot = tid >> 4, which = (tid >> 3) & 1, chunk = tid & 7;
        int xx = which ? 65 : 0;
        int off = (xx * 128 + chunk * 16) ^ ((xx & 7) << 4);
        *(uint4v*)(slab + slot * ROWB + off) = (uint4v){0, 0, 0, 0};
        if (slot < 3)
            *(uint4v*)(aslab + slot * ROWB + off) = (uint4v){0, 0, 0, 0};
    }

    // ---- stage one bf16 feature row into an LDS slab slot (swizzled) ----
    auto stage = [&](char* base, int y) {
        bool zero = (y < 0) || (y >= H_);
        #pragma unroll
        for (int i = 0; i < 2; ++i) {
            int cid = i * 256 + tid;            // 512 = 64 x * 8 c-groups
            int xx = 1 + (cid >> 3);
            int q8 = cid & 7;
            int off = (xx * 128 + q8 * 16) ^ ((xx & 7) << 4);
            uint4v v = (uint4v){0, 0, 0, 0};
            if (!zero)
                v = *(const uint4v*)&tfb[((size_t)y * W_ + (xx - 1)) * CH + q8 * 8];
            *(uint4v*)(base + off) = v;
        }
    };

    // A slab: rows ym-1..ym+1 (fixed for the block)
    #pragma unroll
    for (int dy = 0; dy < 3; ++dy) stage(aslab + dy * ROWB, ym + dy - 1);
    // B ring prologue: rows lo-1, lo, lo+1
    stage(slab + ((lo - 1) & 3) * ROWB, lo - 1);
    stage(slab + ((lo    ) & 3) * ROWB, lo);
    stage(slab + ((lo + 1) & 3) * ROWB, lo + 1);

    float M[16], S[16], W0[16], W1[16];
    #pragma unroll
    for (int r = 0; r < 16; ++r) { M[r] = -INFINITY; S[r] = 0.f; W0[r] = 0.f; W1[r] = 0.f; }

    const int xn = ((w & 1) << 5) + l31;      // this lane's n-column
    const int xm = ((w >> 1) << 5) + l31;     // this lane's A-row position

    __syncthreads();

    for (int yn = lo; yn < lo + 32; ++yn) {
        stage(slab + ((yn + 2) & 3) * ROWB, yn + 2);   // zero-fills past H

        f32x16 acc0, acc1;
        #pragma unroll
        for (int r = 0; r < 16; ++r) { acc0[r] = 0.f; acc1[r] = 0.f; }

        #pragma unroll
        for (int s = 0; s < 9; ++s) {
            int dy = s / 3, dx = s % 3;
            const char* ra = aslab + dy * ROWB;
            const char* rb = slab + ((yn + dy - 1) & 3) * ROWB;
            int xxA = xm + dx;                 // 0..65
            int xxB = xn + dx;
            int baA = xxA * 128, mkA = (xxA & 7) << 4;
            int baB = xxB * 128, mkB = (xxB & 7) << 4;
            #pragma unroll
            for (int q = 0; q < 4; ++q) {
                int qo = q * 32 + h * 16;
                short8 af = *(const short8*)(ra + baA + (qo ^ mkA));
                short8 bf = *(const short8*)(rb + baB + (qo ^ mkB));
                if (s & 1) acc1 = __builtin_amdgcn_mfma_f32_32x32x16_bf16(af, bf, acc1, 0, 0, 0);
                else       acc0 = __builtin_amdgcn_mfma_f32_32x32x16_bf16(af, bf, acc0, 0, 0, 0);
            }
        }

        float av = aab[yn * W_ + xn];
        float bv = bab[yn * W_ + xn];

        // D layout (32x32): col(n) = lane&31, row = (r&3)+8*(r>>2)+4*(lane>>5)
        #pragma unroll
        for (int r = 0; r < 16; ++r) {
            float v  = (acc0[r] + acc1[r]) * SCALE2;
            float nm = fmaxf(M[r], v);
            float sc = exp2f(M[r] - nm);       // exp2(-inf)=0 on first hit
            float p  = exp2f(v - nm);
            S[r]  = S[r]  * sc + p;
            W0[r] = W0[r] * sc + p * av;
            W1[r] = W1[r] * sc + p * bv;
            M[r]  = nm;
        }
        __syncthreads();   // slab writes (yn+2) complete; safe for next iter reads
    }

    // ---- butterfly merge across this wave's 32 n-columns ----
    #pragma unroll
    for (int off = 16; off >= 1; off >>= 1) {
        #pragma unroll
        for (int r = 0; r < 16; ++r) {
            float Mo  = __shfl_xor(M[r],  off);
            float So  = __shfl_xor(S[r],  off);
            float W0o = __shfl_xor(W0[r], off);
            float W1o = __shfl_xor(W1[r], off);
            float nm = fmaxf(M[r], Mo);
            float sA = exp2f(M[r] - nm), sB = exp2f(Mo - nm);
            S[r]  = S[r]  * sA + So  * sB;
            W0[r] = W0[r] * sA + W0o * sB;
            W1[r] = W1[r] * sA + W1o * sB;
            M[r]  = nm;
        }
    }

    if (l31 == 0) {
        #pragma unroll
        for (int r = 0; r < 16; ++r) {
            int mloc = (r & 3) + ((r >> 2) << 3) + (h << 2);
            int m = ((w >> 1) << 5) + mloc;
            mergebuf[w & 1][m] = make_float4(M[r], S[r], W0[r], W1[r]);
        }
    }
    __syncthreads();

    if (tid < 64) {
        float4 A  = mergebuf[0][tid];
        float4 Bv = mergebuf[1][tid];
        float nm = fmaxf(A.x, Bv.x);
        float sA = exp2f(A.x - nm), sB = exp2f(Bv.x - nm);
        part[(((size_t)b * H_ + ym) * 2 + z) * 64 + tid] =
            make_float4(nm,
                        A.y * sA + Bv.y * sB,
                        A.z * sA + Bv.z * sB,
                        A.w * sA + Bv.w * sB);
    }
}

__global__ __launch_bounds__(256) void nlwa_out(
    const float4* __restrict__ part, float* __restrict__ out)
{
    int idx = blockIdx.x * 256 + (int)threadIdx.x;   // 16384 = B*H*64
    int b = idx >> 12, rem = idx & 4095, ym = rem >> 6, m = rem & 63;
    float4 P0 = part[(((size_t)b * H_ + ym) * 2 + 0) * 64 + m];
    float4 P1 = part[(((size_t)b * H_ + ym) * 2 + 1) * 64 + m];
    float nm = fmaxf(P0.x, P1.x);
    float sA = exp2f(P0.x - nm), sB = exp2f(P1.x - nm);
    float Ssum = P0.y * sA + P1.y * sB;
    float inv  = 1.0f / Ssum;
    out[(((size_t)b * 2 + 0) * H_ + ym) * W_ + m] = (P0.z * sA + P1.z * sB) * inv;
    out[(((size_t)b * 2 + 1) * H_ + ym) * W_ + m] = (P0.w * sA + P1.w * sB) * inv;
}

extern "C" void kernel_launch(void* const* d_in, const int* in_sizes, int n_in,
                              void* d_out, int out_size, void* d_ws, size_t ws_size,
                              hipStream_t stream) {
    const float* xlab = (const float*)d_in[0];
    const float* feat = (const float*)d_in[1];
    float* out = (float*)d_out;
    unsigned short* tf = (unsigned short*)d_ws;                    // 2 MB
    float4* part = (float4*)((char*)d_ws + (size_t)2 * 1024 * 1024); // 512 KB

    dim3 gridT(H_, B_);
    feat_to_bf16<<<gridT, 256, 0, stream>>>(feat, tf);
    dim3 gridM(H_, B_, 2);
    nlwa_mfma<<<gridM, 256, 0, stream>>>(xlab, tf, part);
    nlwa_out<<<64, 256, 0, stream>>>(part, out);
}